// Round 9
// baseline (289.110 us; speedup 1.0000x reference)
//
#include <hip/hip_runtime.h>
#include <stdint.h>
#include <stddef.h>

#define VV 3
#define NN 4096
#define DD 512
#define CC 10
#define NBLK 512

typedef unsigned short bf16_t;
typedef __attribute__((ext_vector_type(8))) short bf16x8;
typedef __attribute__((ext_vector_type(4))) float f32x4;

#define MFMA16 __builtin_amdgcn_mfma_f32_16x16x32_bf16

__device__ __forceinline__ float bf2f(unsigned u) {
  union { unsigned u; float f; } c; c.u = u << 16; return c.f;
}
__device__ __forceinline__ bf16_t f2bf(float f) {
  union { float f; unsigned u; } c; c.f = f;
  unsigned r = (c.u + 0x7FFFu + ((c.u >> 16) & 1u)) >> 16;
  return (bf16_t)r;
}
__device__ __forceinline__ float splus(float x) {
  float ax = fabsf(x);
  return fmaxf(x, 0.0f) + log1pf(expf(-ax));
}

// R7-proven relaxed-poll grid barrier (one release fence, relaxed poll w/
// s_sleep, one acquire fence). Correct across graph replays with the memset.
__device__ __forceinline__ void gsync(unsigned* cnt, unsigned target, int t) {
  __syncthreads();
  if (t == 0) {
    __builtin_amdgcn_fence(__ATOMIC_RELEASE, "agent");
    __hip_atomic_fetch_add(cnt, 1u, __ATOMIC_RELAXED, __HIP_MEMORY_SCOPE_AGENT);
    while (__hip_atomic_load(cnt, __ATOMIC_RELAXED, __HIP_MEMORY_SCOPE_AGENT) < target)
      __builtin_amdgcn_s_sleep(16);
    __builtin_amdgcn_fence(__ATOMIC_ACQUIRE, "agent");
  }
  __syncthreads();
}

// ===== phase 0: weights (grid-strided) + A-scan (6 rows per wave) ===========
// mask word layout (ballot-native): word wi of a row, bit b <->
//   column (wi>>2)*256 + 4*b + (wi&3)
__device__ __forceinline__ void dev_prep(int bid, int t,
    const float* __restrict__ A, const float* __restrict__ W1,
    const float* __restrict__ b1, const float* __restrict__ W2,
    const float* __restrict__ W_mlp,
    unsigned long long* __restrict__ mask, float* __restrict__ dinv,
    bf16_t* __restrict__ Wc_t, float* __restrict__ bp, bf16_t* __restrict__ Wm_t)
{
  int w = t >> 6, lane = t & 63;
  int gw = bid * 4 + w;                 // [0, 2048)
  int gt = bid * 256 + t;               // [0, 131072)
  if (gt < VV * DD) {                   // Wm transpose (tiny)
    int v = gt / DD, d = gt - v * DD;
#pragma unroll
    for (int c = 0; c < CC; ++c)
      Wm_t[((size_t)v * 16 + c) * DD + d] = f2bf(W_mlp[((size_t)v * DD + d) * CC + c]);
#pragma unroll
    for (int c = CC; c < 16; ++c) Wm_t[((size_t)v * 16 + c) * DD + d] = 0;
  }
  if (gw < VV * 513) {                  // one Wc/bp row per wave
    int v = gw / 513, dd2 = gw % 513;
    const float* w2 = W2 + (size_t)v * DD * CC;
    const float* src = (dd2 < DD) ? (W1 + ((size_t)v * DD + dd2) * DD) : (b1 + (size_t)v * DD);
    float acc[CC];
#pragma unroll
    for (int c = 0; c < CC; ++c) acc[c] = 0.f;
    for (int it = 0; it < 8; ++it) {
      float wv = src[it * 64 + lane];
      const float* w2r = w2 + (size_t)(it * 64 + lane) * CC;
#pragma unroll
      for (int c = 0; c < CC; ++c) acc[c] += wv * w2r[c];
    }
#pragma unroll
    for (int c = 0; c < CC; ++c) {
#pragma unroll
      for (int s = 32; s; s >>= 1) acc[c] += __shfl_xor(acc[c], s);
    }
    if (lane == 0) {
      if (dd2 < DD) {
#pragma unroll
        for (int c = 0; c < CC; ++c) Wc_t[((size_t)v * 16 + c) * DD + dd2] = f2bf(acc[c]);
#pragma unroll
        for (int c = CC; c < 16; ++c) Wc_t[((size_t)v * 16 + c) * DD + dd2] = 0;
      } else {
#pragma unroll
        for (int c = 0; c < CC; ++c) bp[v * CC + c] = acc[c];
      }
    }
  }
  // A-scan: rows [gw*6, gw*6+6)  (12288 = 2048 waves * 6)
  for (int p = 0; p < 6; ++p) {
    size_t row = (size_t)gw * 6 + p;
    const f32x4* r4 = (const f32x4*)(A + row * NN);
    unsigned long long myw = 0ull;
#pragma unroll 4
    for (int it = 0; it < 16; ++it) {
      f32x4 x = r4[it * 64 + lane];
      unsigned long long q0 = __ballot(x[0] != 0.0f);
      unsigned long long q1 = __ballot(x[1] != 0.0f);
      unsigned long long q2 = __ballot(x[2] != 0.0f);
      unsigned long long q3 = __ballot(x[3] != 0.0f);
      if ((lane >> 2) == it) {
        int k = lane & 3;
        myw = (k == 0) ? q0 : (k == 1) ? q1 : (k == 2) ? q2 : q3;
      }
    }
    mask[row * 64 + lane] = myw;
    int pc = __popcll(myw);
#pragma unroll
    for (int s = 32; s; s >>= 1) pc += __shfl_xor(pc, s);
    if (lane == 0) dinv[row] = 1.0f / sqrtf((float)(pc + 1)); // deg = popc+1 (+I)
  }
}

// ===== phase 1: zs (blocks 0..191): Ps1p[row][8] packed, E = cons+softplus ==
__device__ __forceinline__ void dev_zs(int bid, int t, bf16_t* Bc, bf16_t* Bm,
    const float* __restrict__ X, const bf16_t* __restrict__ Wc_t,
    const bf16_t* __restrict__ Wm_t, const float* __restrict__ b_mlp,
    const float* __restrict__ consensus, const float* __restrict__ dinv,
    unsigned* __restrict__ Ps1p, float* __restrict__ E)
{
  if (bid >= 192) return;
  int v = bid / 64, xb = bid % 64;
  {
    int r = t & 15, ch = t >> 4;
    const bf16_t* sc = Wc_t + (size_t)v * 16 * DD + (size_t)r * DD + ch * 32;
    const bf16_t* sm2 = Wm_t + (size_t)v * 16 * DD + (size_t)r * DD + ch * 32;
    bf16_t* dc = &Bc[r * 520 + ch * 32];
    bf16_t* dm = &Bm[r * 520 + ch * 32];
#pragma unroll
    for (int q = 0; q < 4; ++q) {
      *(bf16x8*)(dc + q * 8) = *(const bf16x8*)(sc + q * 8);
      *(bf16x8*)(dm + q * 8) = *(const bf16x8*)(sm2 + q * 8);
    }
  }
  __syncthreads();
  int w = t >> 6, lane = t & 63;
  int fl = lane & 15, fh = lane >> 4;
  int r0 = xb * 64 + w * 16;
  const float* Xrow = X + ((size_t)v * NN + r0 + fl) * DD;
  f32x4 aP = {0.f, 0.f, 0.f, 0.f}, aM = {0.f, 0.f, 0.f, 0.f};
#pragma unroll
  for (int k = 0; k < 16; ++k) {
    float4 x0 = *(const float4*)(Xrow + k * 32 + fh * 8);
    float4 x1 = *(const float4*)(Xrow + k * 32 + fh * 8 + 4);
    bf16x8 a = { (short)f2bf(x0.x), (short)f2bf(x0.y), (short)f2bf(x0.z), (short)f2bf(x0.w),
                 (short)f2bf(x1.x), (short)f2bf(x1.y), (short)f2bf(x1.z), (short)f2bf(x1.w) };
    bf16x8 b1v = *(const bf16x8*)(&Bc[fl * 520 + k * 32 + fh * 8]);
    aP = MFMA16(a, b1v, aP, 0, 0, 0);
    bf16x8 b2v = *(const bf16x8*)(&Bm[fl * 520 + k * 32 + fh * 8]);
    aM = MFMA16(a, b2v, aM, 0, 0, 0);
  }
  float bmv = (fl < CC) ? b_mlp[v * CC + fl] : 0.f;
#pragma unroll
  for (int g = 0; g < 4; ++g) {
    int j = r0 + fh * 4 + g;
    float dj = dinv[(size_t)v * NN + j];
    float val = aP[g] * dj;
    float part = __shfl_xor(val, 1);            // partner channel fl^1, same j
    if (((fl & 1) == 0) && fl < CC) {
      unsigned pw = (unsigned)f2bf(val) | ((unsigned)f2bf(part) << 16);
      Ps1p[((size_t)v * NN + j) * 8 + (fl >> 1)] = pw;
    }
    if (fl < CC) {
      size_t ad = ((size_t)v * NN + j) * CC + fl;
      E[ad] = consensus[ad] + splus(aM[g] + bmv);
    }
  }
}

// ===== spmm core: 8-lane group per row, gather straight from L2 =============
template<int PASS>
__device__ __forceinline__ void dev_spmm(int bid, int t,
    const unsigned long long* __restrict__ mask, const unsigned* __restrict__ Pin,
    const float* __restrict__ bvec, const float* __restrict__ dinv,
    unsigned* __restrict__ Pout, float* __restrict__ E)
{
  int gid = (bid * 256 + t) >> 3;               // row id
  int s8 = t & 7;
  if (gid >= VV * NN) return;
  int v = gid >> 12;
  const unsigned long long* mrow = mask + (size_t)gid * 64;
  const unsigned* Pv = Pin + (size_t)v * NN * 8;
  float acc[CC];
#pragma unroll
  for (int c = 0; c < CC; ++c) acc[c] = 0.f;
#pragma unroll
  for (int it = 0; it < 8; ++it) {
    int wi = it * 8 + s8;
    unsigned long long bits = mrow[wi];
    int jb = (wi >> 2) * 256 + (wi & 3);
    while (bits) {
      int b = __builtin_ctzll(bits);
      bits &= bits - 1;
      int j = jb + (b << 2);
      const unsigned* pw = Pv + (size_t)j * 8;
      uint4 p0 = *(const uint4*)pw;
      unsigned p4 = pw[4];
      acc[0] += bf2f(p0.x & 0xFFFFu); acc[1] += bf2f(p0.x >> 16);
      acc[2] += bf2f(p0.y & 0xFFFFu); acc[3] += bf2f(p0.y >> 16);
      acc[4] += bf2f(p0.z & 0xFFFFu); acc[5] += bf2f(p0.z >> 16);
      acc[6] += bf2f(p0.w & 0xFFFFu); acc[7] += bf2f(p0.w >> 16);
      acc[8] += bf2f(p4 & 0xFFFFu);   acc[9] += bf2f(p4 >> 16);
    }
  }
#pragma unroll
  for (int c = 0; c < CC; ++c) {
    acc[c] += __shfl_xor(acc[c], 1);
    acc[c] += __shfl_xor(acc[c], 2);
    acc[c] += __shfl_xor(acc[c], 4);
  }
  if (s8 == 0) {
    const unsigned* ps = Pin + (size_t)gid * 8;  // + self (the +I)
    uint4 p0 = *(const uint4*)ps;
    unsigned p4 = ps[4];
    acc[0] += bf2f(p0.x & 0xFFFFu); acc[1] += bf2f(p0.x >> 16);
    acc[2] += bf2f(p0.y & 0xFFFFu); acc[3] += bf2f(p0.y >> 16);
    acc[4] += bf2f(p0.z & 0xFFFFu); acc[5] += bf2f(p0.z >> 16);
    acc[6] += bf2f(p0.w & 0xFFFFu); acc[7] += bf2f(p0.w >> 16);
    acc[8] += bf2f(p4 & 0xFFFFu);   acc[9] += bf2f(p4 >> 16);
    float di = dinv[gid];
    if (PASS == 1) {
#pragma unroll
      for (int c2 = 0; c2 < 5; ++c2) {
        float lo = di * (di * acc[2 * c2]     + bvec[v * CC + 2 * c2]);
        float hi = di * (di * acc[2 * c2 + 1] + bvec[v * CC + 2 * c2 + 1]);
        Pout[(size_t)gid * 8 + c2] = (unsigned)f2bf(lo) | ((unsigned)f2bf(hi) << 16);
      }
    } else {
      float* Eo = E + (size_t)gid * CC;
#pragma unroll
      for (int c = 0; c < CC; ++c)
        Eo[c] = Eo[c] + splus(di * acc[c] + bvec[v * CC + c]);
    }
  }
}

// ===== phase 4: sim partials (blocks 0..15) =================================
__device__ __forceinline__ void dev_sim(int bid, int t, float* sm,
    const float* __restrict__ E, float* __restrict__ partial)
{
  if (bid >= 16) return;
  int n = bid * 256 + t;
  float e0[CC], e1[CC], e2[CC];
#pragma unroll
  for (int c = 0; c < CC; ++c) {
    e0[c] = E[(size_t)(0 * NN + n) * CC + c];
    e1[c] = E[(size_t)(1 * NN + n) * CC + c];
    e2[c] = E[(size_t)(2 * NN + n) * CC + c];
  }
  float n0 = 0, n1 = 0, n2 = 0, d01 = 0, d02 = 0, d12 = 0;
#pragma unroll
  for (int c = 0; c < CC; ++c) { n0 += e0[c]*e0[c]; n1 += e1[c]*e1[c]; n2 += e2[c]*e2[c]; }
  float i0 = 1.0f / fmaxf(sqrtf(n0), 1e-8f);
  float i1 = 1.0f / fmaxf(sqrtf(n1), 1e-8f);
  float i2 = 1.0f / fmaxf(sqrtf(n2), 1e-8f);
#pragma unroll
  for (int c = 0; c < CC; ++c) { d01 += e0[c]*e1[c]; d02 += e0[c]*e2[c]; d12 += e1[c]*e2[c]; }
  sm[0 * 256 + t] = d01 * i0 * i1;
  sm[1 * 256 + t] = d02 * i0 * i2;
  sm[2 * 256 + t] = d12 * i1 * i2;
  __syncthreads();
  for (int s = 128; s; s >>= 1) {
    if (t < s) {
      sm[0*256+t] += sm[0*256+t+s]; sm[1*256+t] += sm[1*256+t+s]; sm[2*256+t] += sm[2*256+t+s];
    }
    __syncthreads();
  }
  if (t == 0) {
    partial[bid * 3 + 0] = sm[0];
    partial[bid * 3 + 1] = sm[256];
    partial[bid * 3 + 2] = sm[512];
  }
}

// ===== phase 5: coef (redundant) + agg (blocks 0..159) ======================
__device__ __forceinline__ void dev_agg(int bid, int t,
    const float* __restrict__ E, const float* __restrict__ partial,
    float* __restrict__ agg)
{
  if (bid >= 160) return;
  float S01 = 0, S02 = 0, S12 = 0;
  for (int b = 0; b < 16; ++b) {
    S01 += partial[b * 3 + 0];
    S02 += partial[b * 3 + 1];
    S12 += partial[b * 3 + 2];
  }
  S01 /= (float)NN; S02 /= (float)NN; S12 /= (float)NN;
  float mx = fmaxf(S01, fmaxf(S02, S12));
  float thr = 0.7f * mx;
  float w01 = (S01 > thr) ? S01 : 0.f;
  float w02 = (S02 > thr) ? S02 : 0.f;
  float m0 = fmaxf(w01, w02);
  float e01 = expf(w01 - m0), e02 = expf(w02 - m0);
  float s0 = e01 + e02;
  float p01 = e01 / s0, p02 = e02 / s0;
  float p12 = 1.0f;                             // row-1 softmax, single edge
  float c0 = (p01 + p02) / 6.0f;
  float c1 = (p12 + p01) / 6.0f;
  float c2 = (p02 + p12) / 6.0f;
  int idx = bid * 256 + t;
  agg[idx] = c0 * E[idx] + c1 * E[NN * CC + idx] + c2 * E[2 * NN * CC + idx];
}

// ===== cooperative single-kernel path =======================================
__global__ __launch_bounds__(256) void k_all(
    const float* __restrict__ A, const float* __restrict__ X,
    const float* __restrict__ consensus,
    const float* __restrict__ W_mlp, const float* __restrict__ b_mlp,
    const float* __restrict__ W1, const float* __restrict__ b1,
    const float* __restrict__ W2, const float* __restrict__ b2,
    unsigned long long* __restrict__ mask,
    bf16_t* __restrict__ Wc_t, bf16_t* __restrict__ Wm_t, float* __restrict__ bp,
    float* __restrict__ dinv, unsigned* __restrict__ Ps1p,
    unsigned* __restrict__ P2p, float* __restrict__ partial,
    unsigned* __restrict__ barcnt, float* __restrict__ E, float* __restrict__ agg)
{
  __shared__ bf16_t Bc[16 * 520];
  __shared__ bf16_t Bm[16 * 520];
  __shared__ float sm[3 * 256];
  int t = threadIdx.x, bid = blockIdx.x;
  dev_prep(bid, t, A, W1, b1, W2, W_mlp, mask, dinv, Wc_t, bp, Wm_t);
  gsync(barcnt, 1 * NBLK, t);
  dev_zs(bid, t, Bc, Bm, X, Wc_t, Wm_t, b_mlp, consensus, dinv, Ps1p, E);
  gsync(barcnt, 2 * NBLK, t);
  dev_spmm<1>(bid, t, mask, Ps1p, bp, dinv, P2p, E);
  gsync(barcnt, 3 * NBLK, t);
  dev_spmm<2>(bid, t, mask, P2p, b2, dinv, (unsigned*)nullptr, E);
  gsync(barcnt, 4 * NBLK, t);
  dev_sim(bid, t, sm, E, partial);
  gsync(barcnt, 5 * NBLK, t);
  dev_agg(bid, t, E, partial, agg);
}

// ===== fallback: same phases as plain kernels ===============================
__global__ __launch_bounds__(256) void k_one(int ph,
    const float* A, const float* X, const float* consensus,
    const float* W_mlp, const float* b_mlp,
    const float* W1, const float* b1, const float* W2, const float* b2,
    unsigned long long* mask, bf16_t* Wc_t, bf16_t* Wm_t, float* bp,
    float* dinv, unsigned* Ps1p, unsigned* P2p, float* partial,
    float* E, float* agg)
{
  __shared__ bf16_t Bc[16 * 520];
  __shared__ bf16_t Bm[16 * 520];
  __shared__ float sm[3 * 256];
  int t = threadIdx.x, bid = blockIdx.x;
  if (ph == 0)      dev_prep(bid, t, A, W1, b1, W2, W_mlp, mask, dinv, Wc_t, bp, Wm_t);
  else if (ph == 1) dev_zs(bid, t, Bc, Bm, X, Wc_t, Wm_t, b_mlp, consensus, dinv, Ps1p, E);
  else if (ph == 2) dev_spmm<1>(bid, t, mask, Ps1p, bp, dinv, P2p, E);
  else if (ph == 3) dev_spmm<2>(bid, t, mask, P2p, b2, dinv, (unsigned*)nullptr, E);
  else if (ph == 4) dev_sim(bid, t, sm, E, partial);
  else              dev_agg(bid, t, E, partial, agg);
}

// ---------------------------------------------------------------------------
extern "C" void kernel_launch(void* const* d_in, const int* in_sizes, int n_in,
                              void* d_out, int out_size, void* d_ws, size_t ws_size,
                              hipStream_t stream)
{
  (void)in_sizes; (void)n_in; (void)out_size;
  const float* X         = (const float*)d_in[0];
  const float* A         = (const float*)d_in[1];
  const float* consensus = (const float*)d_in[2];
  const float* W_mlp     = (const float*)d_in[3];
  const float* b_mlp     = (const float*)d_in[4];
  const float* W1        = (const float*)d_in[5];
  const float* b1        = (const float*)d_in[6];
  const float* W2        = (const float*)d_in[7];
  const float* b2        = (const float*)d_in[8];
  float* Eout = (float*)d_out;
  float* aggout = Eout + (size_t)VV * NN * CC;

  char* ws = (char*)d_ws;
  size_t off = 0;
  auto alloc = [&](size_t b) { char* p = ws + off; off += (b + 255) & ~(size_t)255; return p; };
  unsigned long long* mask = (unsigned long long*)alloc((size_t)VV * NN * 64 * 8);
  bf16_t* Wc_t  = (bf16_t*)alloc((size_t)VV * 16 * DD * 2);
  bf16_t* Wm_t  = (bf16_t*)alloc((size_t)VV * 16 * DD * 2);
  float*  bp    = (float*) alloc((size_t)VV * CC * 4);
  float*  dinv  = (float*) alloc((size_t)VV * NN * 4);
  unsigned* Ps1p = (unsigned*)alloc((size_t)VV * NN * 8 * 4);
  unsigned* P2p  = (unsigned*)alloc((size_t)VV * NN * 8 * 4);
  float*  partial = (float*)alloc(16 * 3 * 4);
  unsigned* barcnt = (unsigned*)alloc(256);
  if (off > ws_size) return;

  hipMemsetAsync(barcnt, 0, 4, stream);          // barrier epoch counter = 0

  void* kargs[] = {
    (void*)&A, (void*)&X, (void*)&consensus, (void*)&W_mlp, (void*)&b_mlp,
    (void*)&W1, (void*)&b1, (void*)&W2, (void*)&b2,
    (void*)&mask, (void*)&Wc_t, (void*)&Wm_t, (void*)&bp, (void*)&dinv,
    (void*)&Ps1p, (void*)&P2p, (void*)&partial, (void*)&barcnt,
    (void*)&Eout, (void*)&aggout
  };
  hipError_t err = hipLaunchCooperativeKernel((const void*)k_all, dim3(NBLK),
                                              dim3(256), kargs, 0, stream);
  if (err != hipSuccess) {
    // plain-kernel fallback: same device code, kernel boundaries as barriers
    k_one<<<NBLK, 256, 0, stream>>>(0, A, X, consensus, W_mlp, b_mlp, W1, b1, W2, b2,
                                    mask, Wc_t, Wm_t, bp, dinv, Ps1p, P2p, partial, Eout, aggout);
    k_one<<<192, 256, 0, stream>>>(1, A, X, consensus, W_mlp, b_mlp, W1, b1, W2, b2,
                                   mask, Wc_t, Wm_t, bp, dinv, Ps1p, P2p, partial, Eout, aggout);
    k_one<<<NBLK, 256, 0, stream>>>(2, A, X, consensus, W_mlp, b_mlp, W1, b1, W2, b2,
                                    mask, Wc_t, Wm_t, bp, dinv, Ps1p, P2p, partial, Eout, aggout);
    k_one<<<NBLK, 256, 0, stream>>>(3, A, X, consensus, W_mlp, b_mlp, W1, b1, W2, b2,
                                    mask, Wc_t, Wm_t, bp, dinv, Ps1p, P2p, partial, Eout, aggout);
    k_one<<<16, 256, 0, stream>>>(4, A, X, consensus, W_mlp, b_mlp, W1, b1, W2, b2,
                                  mask, Wc_t, Wm_t, bp, dinv, Ps1p, P2p, partial, Eout, aggout);
    k_one<<<160, 256, 0, stream>>>(5, A, X, consensus, W_mlp, b_mlp, W1, b1, W2, b2,
                                   mask, Wc_t, Wm_t, bp, dinv, Ps1p, P2p, partial, Eout, aggout);
  }
}

// Round 10
// 81.071 us; speedup vs baseline: 3.5661x; 3.5661x over previous
//
#include <hip/hip_runtime.h>
#include <stdint.h>
#include <stddef.h>

#define VV 3
#define NN 4096
#define DD 512
#define CC 10

typedef unsigned short bf16_t;
typedef __attribute__((ext_vector_type(8))) short bf16x8;
typedef __attribute__((ext_vector_type(4))) float f32x4;

#define MFMA16 __builtin_amdgcn_mfma_f32_16x16x32_bf16

__device__ __forceinline__ float bf2f(unsigned u) {
  union { unsigned u; float f; } c; c.u = u << 16; return c.f;
}
__device__ __forceinline__ bf16_t f2bf(float f) {
  union { float f; unsigned u; } c; c.f = f;
  unsigned r = (c.u + 0x7FFFu + ((c.u >> 16) & 1u)) >> 16;
  return (bf16_t)r;
}
__device__ __forceinline__ float splus(float x) {
  float ax = fabsf(x);
  return fmaxf(x, 0.0f) + log1pf(expf(-ax));
}

// ---------------- K1: fused prep -------------------------------------------
// blocks [0,3072):      A -> bitmask (ballot-native layout) + dinv
// blocks [3072,3457):   Wc_t = (W1@W2)^T bf16 (padded 16 rows), bp = b1@W2
// blocks [3457,3463):   Wm_t = W_mlp^T bf16 (padded 16 rows)
// mask word layout: word wi of a row, bit b <-> column (wi>>2)*256 + 4b + (wi&3)
// NOTE: plain (cacheable) loads on A — L3 retains ~80MB of A across graph
// replays (R9: FETCH 120MB < 201MB); nontemporal forfeited that (R8 regression).
__global__ __launch_bounds__(256) void k_prep(const float* __restrict__ A,
    const float* __restrict__ W1, const float* __restrict__ b1,
    const float* __restrict__ W2, const float* __restrict__ W_mlp,
    unsigned long long* __restrict__ mask, float* __restrict__ dinv,
    bf16_t* __restrict__ Wc_t, float* __restrict__ bp, bf16_t* __restrict__ Wm_t)
{
  int t = threadIdx.x;
  int w = t >> 6, lane = t & 63;
  if (blockIdx.x < VV * NN / 4) {
    size_t row = (size_t)blockIdx.x * 4 + w;     // one row per wave
    const f32x4* r4 = (const f32x4*)(A + row * NN);
    unsigned long long myw = 0ull;
#pragma unroll 8
    for (int it = 0; it < 16; ++it) {
      f32x4 x = r4[it * 64 + lane];
      unsigned long long q0 = __ballot(x[0] != 0.0f);
      unsigned long long q1 = __ballot(x[1] != 0.0f);
      unsigned long long q2 = __ballot(x[2] != 0.0f);
      unsigned long long q3 = __ballot(x[3] != 0.0f);
      if ((lane >> 2) == it) {
        int k = lane & 3;
        myw = (k == 0) ? q0 : (k == 1) ? q1 : (k == 2) ? q2 : q3;
      }
    }
    mask[row * 64 + lane] = myw;
    int pc = __popcll(myw);
#pragma unroll
    for (int s = 32; s; s >>= 1) pc += __shfl_xor(pc, s);
    if (lane == 0) dinv[row] = 1.0f / sqrtf((float)(pc + 1)); // deg = popc+1 (+I)
  } else if (blockIdx.x < VV * NN / 4 + 385) {
    int wid = (blockIdx.x - VV * NN / 4) * 4 + w;
    if (wid >= VV * 513) return;
    int v = wid / 513, dd2 = wid % 513;
    const float* w2 = W2 + (size_t)v * DD * CC;
    const float* src = (dd2 < DD) ? (W1 + ((size_t)v * DD + dd2) * DD) : (b1 + (size_t)v * DD);
    float acc[CC];
#pragma unroll
    for (int c = 0; c < CC; ++c) acc[c] = 0.f;
    for (int it = 0; it < 8; ++it) {
      float wv = src[it * 64 + lane];
      const float* w2r = w2 + (size_t)(it * 64 + lane) * CC;
#pragma unroll
      for (int c = 0; c < CC; ++c) acc[c] += wv * w2r[c];
    }
#pragma unroll
    for (int c = 0; c < CC; ++c) {
#pragma unroll
      for (int s = 32; s; s >>= 1) acc[c] += __shfl_xor(acc[c], s);
    }
    if (lane == 0) {
      if (dd2 < DD) {
#pragma unroll
        for (int c = 0; c < CC; ++c) Wc_t[((size_t)v * 16 + c) * DD + dd2] = f2bf(acc[c]);
#pragma unroll
        for (int c = CC; c < 16; ++c) Wc_t[((size_t)v * 16 + c) * DD + dd2] = 0;
      } else {
#pragma unroll
        for (int c = 0; c < CC; ++c) bp[v * CC + c] = acc[c];
      }
    }
  } else {
    int idx = (blockIdx.x - (VV * NN / 4 + 385)) * 256 + t;
    if (idx >= VV * DD) return;
    int v = idx / DD, d = idx % DD;
#pragma unroll
    for (int c = 0; c < CC; ++c)
      Wm_t[((size_t)v * 16 + c) * DD + d] = f2bf(W_mlp[((size_t)v * DD + d) * CC + c]);
#pragma unroll
    for (int c = CC; c < 16; ++c) Wm_t[((size_t)v * 16 + c) * DD + d] = 0;
  }
}

// ---------------- K2: Ps1p[v][c/2][j] = packed bf16 pair of dinv_j*(X·Wc) ---
//                      E[v,j,c] = consensus + softplus(X·Wm + bm)
__global__ __launch_bounds__(256) void k_zs(
    const float* __restrict__ X,
    const bf16_t* __restrict__ Wc_t, const bf16_t* __restrict__ Wm_t,
    const float* __restrict__ b_mlp, const float* __restrict__ consensus,
    const float* __restrict__ dinv,
    unsigned* __restrict__ Ps1p, float* __restrict__ E)
{
  __shared__ bf16_t Bc[16 * 520];
  __shared__ bf16_t Bm[16 * 520];
  int v = blockIdx.y;
  int t = threadIdx.x;
  {
    int r = t & 15, ch = t >> 4;
    const bf16_t* sc = Wc_t + (size_t)v * 16 * DD + (size_t)r * DD + ch * 32;
    const bf16_t* sm = Wm_t + (size_t)v * 16 * DD + (size_t)r * DD + ch * 32;
    bf16_t* dc = &Bc[r * 520 + ch * 32];
    bf16_t* dm = &Bm[r * 520 + ch * 32];
#pragma unroll
    for (int q = 0; q < 4; ++q) {
      *(bf16x8*)(dc + q * 8) = *(const bf16x8*)(sc + q * 8);
      *(bf16x8*)(dm + q * 8) = *(const bf16x8*)(sm + q * 8);
    }
  }
  __syncthreads();
  int w = t >> 6, lane = t & 63;
  int fl = lane & 15, fh = lane >> 4;
  int r0 = blockIdx.x * 64 + w * 16;
  const float* Xrow = X + ((size_t)v * NN + r0 + fl) * DD;
  f32x4 aP = {0.f, 0.f, 0.f, 0.f}, aM = {0.f, 0.f, 0.f, 0.f};
#pragma unroll
  for (int k = 0; k < 16; ++k) {
    float4 x0 = *(const float4*)(Xrow + k * 32 + fh * 8);
    float4 x1 = *(const float4*)(Xrow + k * 32 + fh * 8 + 4);
    bf16x8 a = { (short)f2bf(x0.x), (short)f2bf(x0.y), (short)f2bf(x0.z), (short)f2bf(x0.w),
                 (short)f2bf(x1.x), (short)f2bf(x1.y), (short)f2bf(x1.z), (short)f2bf(x1.w) };
    bf16x8 b1v = *(const bf16x8*)(&Bc[fl * 520 + k * 32 + fh * 8]);
    aP = MFMA16(a, b1v, aP, 0, 0, 0);
    bf16x8 b2v = *(const bf16x8*)(&Bm[fl * 520 + k * 32 + fh * 8]);
    aM = MFMA16(a, b2v, aM, 0, 0, 0);
  }
  float bmv = (fl < CC) ? b_mlp[v * CC + fl] : 0.f;
#pragma unroll
  for (int g = 0; g < 4; ++g) {
    int j = r0 + fh * 4 + g;
    float dj = dinv[(size_t)v * NN + j];
    float val = aP[g] * dj;
    float part = __shfl_xor(val, 1);            // partner channel fl^1, same j
    if (((fl & 1) == 0) && fl < CC) {
      unsigned pw = (unsigned)f2bf(val) | ((unsigned)f2bf(part) << 16);
      Ps1p[((size_t)v * 5 + (fl >> 1)) * NN + j] = pw;
    }
    if (fl < CC) {
      size_t ad = ((size_t)v * NN + j) * CC + fl;
      E[ad] = consensus[ad] + splus(aM[g] + bmv);
    }
  }
}

// ---- shared gather core: 8-lane group per row, ballot-native bit decode ----
#define SPMM_PROLOG(SRC_) \
  __shared__ unsigned PsL[5 * NN];  /* 80 KB */ \
  int v = blockIdx.y; \
  int t = threadIdx.x; \
  { \
    const uint4* src_ = (const uint4*)((SRC_) + (size_t)v * 5 * NN); \
    uint4* dst_ = (uint4*)PsL; \
    _Pragma("unroll") \
    for (int q = 0; q < 20; ++q) dst_[q * 256 + t] = src_[q * 256 + t]; \
  } \
  __syncthreads(); \
  int w = t >> 6, g = (t >> 3) & 7, s = t & 7; \
  int i = blockIdx.x * 32 + w * 8 + g; \
  const unsigned long long* mrow = mask + ((size_t)v * NN + i) * 64; \
  float acc[CC]; \
  _Pragma("unroll") \
  for (int c = 0; c < CC; ++c) acc[c] = 0.f; \
  _Pragma("unroll") \
  for (int it = 0; it < 8; ++it) { \
    int wi = it * 8 + s; \
    unsigned long long bits = mrow[wi]; \
    int jb = (wi >> 2) * 256 + (wi & 3); \
    while (bits) { \
      int b = __builtin_ctzll(bits); \
      bits &= bits - 1; \
      int j = jb + (b << 2); \
      _Pragma("unroll") \
      for (int c2 = 0; c2 < 5; ++c2) { \
        unsigned pw = PsL[c2 * NN + j]; \
        acc[2 * c2]     += bf2f(pw & 0xFFFFu); \
        acc[2 * c2 + 1] += bf2f(pw >> 16); \
      } \
    } \
  } \
  _Pragma("unroll") \
  for (int c = 0; c < CC; ++c) { \
    acc[c] += __shfl_xor(acc[c], 1); \
    acc[c] += __shfl_xor(acc[c], 2); \
    acc[c] += __shfl_xor(acc[c], 4); \
  }

// ---------------- K3: P2p[c/2][i] = pack(di*(di*(Ahat@Ps1)[i,c] + bp_c)) ----
__global__ __launch_bounds__(256) void k_spmm1(
    const unsigned long long* __restrict__ mask, const unsigned* __restrict__ Ps1p,
    const float* __restrict__ bp, const float* __restrict__ dinv,
    unsigned* __restrict__ P2p)
{
  SPMM_PROLOG(Ps1p)
  if (s == 0) {
    float di = dinv[(size_t)v * NN + i];
#pragma unroll
    for (int c2 = 0; c2 < 5; ++c2) {             // + self (the +I)
      unsigned pw = PsL[c2 * NN + i];
      acc[2 * c2]     += bf2f(pw & 0xFFFFu);
      acc[2 * c2 + 1] += bf2f(pw >> 16);
    }
#pragma unroll
    for (int c2 = 0; c2 < 5; ++c2) {
      float lo = di * (di * acc[2 * c2]     + bp[v * CC + 2 * c2]);
      float hi = di * (di * acc[2 * c2 + 1] + bp[v * CC + 2 * c2 + 1]);
      P2p[((size_t)v * 5 + c2) * NN + i] = (unsigned)f2bf(lo) | ((unsigned)f2bf(hi) << 16);
    }
  }
}

// ---------------- K4: E += softplus(di*(Ahat@P2) + b2) ----------------------
__global__ __launch_bounds__(256) void k_spmm2(
    const unsigned long long* __restrict__ mask, const unsigned* __restrict__ P2p,
    const float* __restrict__ b2, const float* __restrict__ dinv,
    float* __restrict__ E)
{
  SPMM_PROLOG(P2p)
  if (s == 0) {
    float di = dinv[(size_t)v * NN + i];
#pragma unroll
    for (int c2 = 0; c2 < 5; ++c2) {             // + self (the +I)
      unsigned pw = PsL[c2 * NN + i];
      acc[2 * c2]     += bf2f(pw & 0xFFFFu);
      acc[2 * c2 + 1] += bf2f(pw >> 16);
    }
    float* Eo = E + ((size_t)v * NN + i) * CC;
#pragma unroll
    for (int c = 0; c < CC; ++c)
      Eo[c] = Eo[c] + splus(di * acc[c] + b2[v * CC + c]);
  }
}

// ---------------- K5: per-block partial sums of pairwise cosine dots --------
__global__ __launch_bounds__(256) void k_sim(const float* __restrict__ E,
                                             float* __restrict__ partial)
{
  __shared__ float sm[3][256];
  int t = threadIdx.x;
  int n = blockIdx.x * 256 + t;
  float e0[CC], e1[CC], e2[CC];
#pragma unroll
  for (int c = 0; c < CC; ++c) {
    e0[c] = E[(size_t)(0 * NN + n) * CC + c];
    e1[c] = E[(size_t)(1 * NN + n) * CC + c];
    e2[c] = E[(size_t)(2 * NN + n) * CC + c];
  }
  float n0 = 0, n1 = 0, n2 = 0, d01 = 0, d02 = 0, d12 = 0;
#pragma unroll
  for (int c = 0; c < CC; ++c) { n0 += e0[c]*e0[c]; n1 += e1[c]*e1[c]; n2 += e2[c]*e2[c]; }
  float i0 = 1.0f / fmaxf(sqrtf(n0), 1e-8f);
  float i1 = 1.0f / fmaxf(sqrtf(n1), 1e-8f);
  float i2 = 1.0f / fmaxf(sqrtf(n2), 1e-8f);
#pragma unroll
  for (int c = 0; c < CC; ++c) { d01 += e0[c]*e1[c]; d02 += e0[c]*e2[c]; d12 += e1[c]*e2[c]; }
  sm[0][t] = d01 * i0 * i1;
  sm[1][t] = d02 * i0 * i2;
  sm[2][t] = d12 * i1 * i2;
  __syncthreads();
  for (int s = 128; s; s >>= 1) {
    if (t < s) { sm[0][t] += sm[0][t+s]; sm[1][t] += sm[1][t+s]; sm[2][t] += sm[2][t+s]; }
    __syncthreads();
  }
  if (t == 0) {
    partial[blockIdx.x * 3 + 0] = sm[0][0];
    partial[blockIdx.x * 3 + 1] = sm[1][0];
    partial[blockIdx.x * 3 + 2] = sm[2][0];
  }
}

// ---------------- K6: coef (redundant per block) + agg ----------------------
__global__ __launch_bounds__(256) void k_aggc(const float* __restrict__ E,
    const float* __restrict__ partial, float* __restrict__ agg)
{
  float S01 = 0, S02 = 0, S12 = 0;
  for (int b = 0; b < 16; ++b) {
    S01 += partial[b * 3 + 0];
    S02 += partial[b * 3 + 1];
    S12 += partial[b * 3 + 2];
  }
  S01 /= (float)NN; S02 /= (float)NN; S12 /= (float)NN;
  float mx = fmaxf(S01, fmaxf(S02, S12));
  float thr = 0.7f * mx;
  float w01 = (S01 > thr) ? S01 : 0.f;
  float w02 = (S02 > thr) ? S02 : 0.f;
  float m0 = fmaxf(w01, w02);
  float e01 = expf(w01 - m0), e02 = expf(w02 - m0);
  float s0 = e01 + e02;
  float p01 = e01 / s0, p02 = e02 / s0;
  float p12 = 1.0f;                      // row-1 softmax over its single edge
  float c0 = (p01 + p02) / 6.0f;
  float c1 = (p12 + p01) / 6.0f;
  float c2 = (p02 + p12) / 6.0f;
  int idx = blockIdx.x * 256 + threadIdx.x;
  agg[idx] = c0 * E[idx] + c1 * E[NN * CC + idx] + c2 * E[2 * NN * CC + idx];
}

// ---------------------------------------------------------------------------
extern "C" void kernel_launch(void* const* d_in, const int* in_sizes, int n_in,
                              void* d_out, int out_size, void* d_ws, size_t ws_size,
                              hipStream_t stream)
{
  (void)in_sizes; (void)n_in; (void)out_size;
  const float* X         = (const float*)d_in[0];
  const float* A         = (const float*)d_in[1];
  const float* consensus = (const float*)d_in[2];
  const float* W_mlp     = (const float*)d_in[3];
  const float* b_mlp     = (const float*)d_in[4];
  const float* W1        = (const float*)d_in[5];
  const float* b1        = (const float*)d_in[6];
  const float* W2        = (const float*)d_in[7];
  const float* b2        = (const float*)d_in[8];
  float* Eout = (float*)d_out;
  float* aggout = Eout + (size_t)VV * NN * CC;

  char* ws = (char*)d_ws;
  size_t off = 0;
  auto alloc = [&](size_t b) { char* p = ws + off; off += (b + 255) & ~(size_t)255; return p; };
  unsigned long long* mask = (unsigned long long*)alloc((size_t)VV * NN * 64 * 8);
  bf16_t* Wc_t  = (bf16_t*)alloc((size_t)VV * 16 * DD * 2);
  bf16_t* Wm_t  = (bf16_t*)alloc((size_t)VV * 16 * DD * 2);
  float*  bp    = (float*) alloc((size_t)VV * CC * 4);
  float*  dinv  = (float*) alloc((size_t)VV * NN * 4);
  unsigned* Ps1p = (unsigned*)alloc((size_t)VV * 5 * NN * 4);
  unsigned* P2p  = (unsigned*)alloc((size_t)VV * 5 * NN * 4);
  float*  partial = (float*)alloc(16 * 3 * 4);
  if (off > ws_size) return;

  k_prep <<<VV * NN / 4 + 385 + 6, 256, 0, stream>>>(A, W1, b1, W2, W_mlp,
                                                     mask, dinv, Wc_t, bp, Wm_t);
  k_zs   <<<dim3(NN / 64, VV), 256, 0, stream>>>(X, Wc_t, Wm_t, b_mlp, consensus,
                                                 dinv, Ps1p, Eout);
  k_spmm1<<<dim3(NN / 32, VV), 256, 0, stream>>>(mask, Ps1p, bp, dinv, P2p);
  k_spmm2<<<dim3(NN / 32, VV), 256, 0, stream>>>(mask, P2p, b2, dinv, Eout);
  k_sim  <<<NN / 256, 256, 0, stream>>>(Eout, partial);
  k_aggc <<<160, 256, 0, stream>>>(Eout, partial, aggout);
}